// Round 2
// baseline (162.818 us; speedup 1.0000x reference)
//
#include <hip/hip_runtime.h>

constexpr int B = 2, C = 32, H = 96, W = 128, D = 48, NSRC = 2;
constexpr int NV = NSRC + 1;
constexpr int HWsz = H * W;

// ws layout (floats)
constexpr int PROJ_OFF  = 0;                         // 12 * NSRC*B = 48
constexpr int SRC_T_OFF = 64;                        // NSRC*B*HW*C
constexpr int REF_T_OFF = SRC_T_OFF + NSRC * B * HWsz * C;
constexpr int WS_FLOATS = REF_T_OFF + B * HWsz * C;

// ---------------------------------------------------------------------------
// Setup: per (view, b) compute rot(3x3) + trans(3) of  src_p @ inv(ref_p)
// ---------------------------------------------------------------------------
__global__ void setup_proj(const float* __restrict__ ref_proj,
                           const float* __restrict__ src_projs,
                           float* __restrict__ ws) {
  int t = threadIdx.x;
  if (t >= NSRC * B) return;
  int v = t / B, b = t % B;
  const float* rp = ref_proj + b * 32;
  const float* sp = src_projs + (v * B + b) * 32;

  double Kr[3][3], Er[3][4], Ks[3][3], Es[3][4];
  for (int r = 0; r < 3; r++)
    for (int c = 0; c < 3; c++) { Kr[r][c] = rp[16 + r * 4 + c]; Ks[r][c] = sp[16 + r * 4 + c]; }
  for (int r = 0; r < 3; r++)
    for (int c = 0; c < 4; c++) { Er[r][c] = rp[r * 4 + c]; Es[r][c] = sp[r * 4 + c]; }

  double Ar[3][3], tr[3], As[3][3], ts[3];
  for (int r = 0; r < 3; r++) {
    for (int c = 0; c < 3; c++) {
      double a = 0, s = 0;
      for (int k = 0; k < 3; k++) { a += Kr[r][k] * Er[k][c]; s += Ks[r][k] * Es[k][c]; }
      Ar[r][c] = a; As[r][c] = s;
    }
    double a = 0, s = 0;
    for (int k = 0; k < 3; k++) { a += Kr[r][k] * Er[k][3]; s += Ks[r][k] * Es[k][3]; }
    tr[r] = a; ts[r] = s;
  }

  double det = Ar[0][0] * (Ar[1][1] * Ar[2][2] - Ar[1][2] * Ar[2][1])
             - Ar[0][1] * (Ar[1][0] * Ar[2][2] - Ar[1][2] * Ar[2][0])
             + Ar[0][2] * (Ar[1][0] * Ar[2][1] - Ar[1][1] * Ar[2][0]);
  double inv[3][3];
  inv[0][0] =  (Ar[1][1] * Ar[2][2] - Ar[1][2] * Ar[2][1]) / det;
  inv[0][1] = -(Ar[0][1] * Ar[2][2] - Ar[0][2] * Ar[2][1]) / det;
  inv[0][2] =  (Ar[0][1] * Ar[1][2] - Ar[0][2] * Ar[1][1]) / det;
  inv[1][0] = -(Ar[1][0] * Ar[2][2] - Ar[1][2] * Ar[2][0]) / det;
  inv[1][1] =  (Ar[0][0] * Ar[2][2] - Ar[0][2] * Ar[2][0]) / det;
  inv[1][2] = -(Ar[0][0] * Ar[1][2] - Ar[0][2] * Ar[1][0]) / det;
  inv[2][0] =  (Ar[1][0] * Ar[2][1] - Ar[1][1] * Ar[2][0]) / det;
  inv[2][1] = -(Ar[0][0] * Ar[2][1] - Ar[0][1] * Ar[2][0]) / det;
  inv[2][2] =  (Ar[0][0] * Ar[1][1] - Ar[0][1] * Ar[1][0]) / det;

  double rot[3][3], trans[3];
  for (int r = 0; r < 3; r++)
    for (int c = 0; c < 3; c++) {
      double a = 0;
      for (int k = 0; k < 3; k++) a += As[r][k] * inv[k][c];
      rot[r][c] = a;
    }
  for (int r = 0; r < 3; r++) {
    double a = 0;
    for (int k = 0; k < 3; k++) a += rot[r][k] * tr[k];
    trans[r] = ts[r] - a;
  }

  float* o = ws + PROJ_OFF + t * 12;
  for (int r = 0; r < 3; r++)
    for (int c = 0; c < 3; c++) o[r * 3 + c] = (float)rot[r][c];
  for (int r = 0; r < 3; r++) o[9 + r] = (float)trans[r];
}

// ---------------------------------------------------------------------------
// Transpose [plane][C][HW] -> [plane][HW][C] via LDS tile (256 hw x 32 c).
// ---------------------------------------------------------------------------
__global__ __launch_bounds__(256) void transpose_cl(const float* __restrict__ in,
                                                    float* __restrict__ out) {
  __shared__ float lds[C][257];
  constexpr int BLKS_PER_PLANE = HWsz / 256;
  int plane = blockIdx.x / BLKS_PER_PLANE;
  int hw0 = (blockIdx.x % BLKS_PER_PLANE) * 256;
  int t = threadIdx.x;
  const float* ip = in + (size_t)plane * C * HWsz + hw0;
#pragma unroll
  for (int c = 0; c < C; c++) lds[c][t] = ip[c * HWsz + t];
  __syncthreads();
  float* op = out + ((size_t)plane * HWsz + hw0) * C;
#pragma unroll
  for (int k = 0; k < C; k++) {
    int i = k * 256 + t;
    op[i] = lds[i & (C - 1)][i >> 5];  // c = i%32, hw_local = i/32
  }
}

static __device__ __forceinline__ float4 f4scale(float s, float4 a) {
  return make_float4(s * a.x, s * a.y, s * a.z, s * a.w);
}
static __device__ __forceinline__ float4 f4fma(float s, float4 a, float4 acc) {
  return make_float4(fmaf(s, a.x, acc.x), fmaf(s, a.y, acc.y),
                     fmaf(s, a.z, acc.z), fmaf(s, a.w, acc.w));
}

// ---------------------------------------------------------------------------
// Cost kernel, channel-last: one thread per (b,d,h,w); 8 float4 groups.
// ---------------------------------------------------------------------------
__global__ __launch_bounds__(256) void cost_cl_kernel(
    const float* __restrict__ reft, const float* __restrict__ srct,
    const float* __restrict__ dvals, const float* __restrict__ wreg,
    const float* __restrict__ breg, const float* __restrict__ pr,
    float* __restrict__ cost_out) {
  int idx = blockIdx.x * 256 + threadIdx.x;
  if (idx >= B * D * H * W) return;
  int w = idx % W;
  int h = (idx / W) % H;
  int d = (idx / (W * H)) % D;
  int b = idx / (W * H * D);
  float depth = dvals[b * D + d];
  float fx = (float)w, fy = (float)h;

  const float4* cp[NSRC][4];
  float wgt[NSRC][4];
#pragma unroll
  for (int v = 0; v < NSRC; v++) {
    const float* p = pr + (v * B + b) * 12;
    float X = (p[0] * fx + p[1] * fy + p[2]) * depth + p[9];
    float Y = (p[3] * fx + p[4] * fy + p[5]) * depth + p[10];
    float Z = (p[6] * fx + p[7] * fy + p[8]) * depth + p[11];
    float px = X / Z, py = Y / Z;
    float x0f = floorf(px), y0f = floorf(py);
    float wx = px - x0f, wy = py - y0f;
    int x0 = (int)x0f, y0 = (int)y0f;
    int x1 = x0 + 1, y1 = y0 + 1;
    float vx0 = (x0 >= 0 && x0 < W) ? 1.f : 0.f;
    float vx1 = (x1 >= 0 && x1 < W) ? 1.f : 0.f;
    float vy0 = (y0 >= 0 && y0 < H) ? 1.f : 0.f;
    float vy1 = (y1 >= 0 && y1 < H) ? 1.f : 0.f;
    int cx0 = min(max(x0, 0), W - 1), cx1 = min(max(x1, 0), W - 1);
    int cy0 = min(max(y0, 0), H - 1), cy1 = min(max(y1, 0), H - 1);
    const float4* base = (const float4*)srct + (size_t)(v * B + b) * HWsz * (C / 4);
    cp[v][0] = base + (cy0 * W + cx0) * (C / 4);
    cp[v][1] = base + (cy0 * W + cx1) * (C / 4);
    cp[v][2] = base + (cy1 * W + cx0) * (C / 4);
    cp[v][3] = base + (cy1 * W + cx1) * (C / 4);
    wgt[v][0] = (1.f - wx) * (1.f - wy) * vx0 * vy0;
    wgt[v][1] = wx * (1.f - wy) * vx1 * vy0;
    wgt[v][2] = (1.f - wx) * wy * vx0 * vy1;
    wgt[v][3] = wx * wy * vx1 * vy1;
  }

  const float4* r4 = (const float4*)reft + (size_t)(b * HWsz + h * W + w) * (C / 4);
  const float4* wr4 = (const float4*)wreg;
  const float inv_nv = 1.f / (float)NV;
  float cost = 0.f;
#pragma unroll 4
  for (int g = 0; g < C / 4; g++) {
    float4 r = r4[g];
    float4 s = r;
    float4 sq = make_float4(r.x * r.x, r.y * r.y, r.z * r.z, r.w * r.w);
#pragma unroll
    for (int v = 0; v < NSRC; v++) {
      float4 c0 = cp[v][0][g];
      float4 c1 = cp[v][1][g];
      float4 c2 = cp[v][2][g];
      float4 c3 = cp[v][3][g];
      float4 smp = f4scale(wgt[v][0], c0);
      smp = f4fma(wgt[v][1], c1, smp);
      smp = f4fma(wgt[v][2], c2, smp);
      smp = f4fma(wgt[v][3], c3, smp);
      s.x += smp.x; s.y += smp.y; s.z += smp.z; s.w += smp.w;
      sq.x = fmaf(smp.x, smp.x, sq.x);
      sq.y = fmaf(smp.y, smp.y, sq.y);
      sq.z = fmaf(smp.z, smp.z, sq.z);
      sq.w = fmaf(smp.w, smp.w, sq.w);
    }
    float4 wv = wr4[g];
    float mx = s.x * inv_nv, my = s.y * inv_nv, mz = s.z * inv_nv, mw = s.w * inv_nv;
    cost += (sq.x * inv_nv - mx * mx) * wv.x;
    cost += (sq.y * inv_nv - my * my) * wv.y;
    cost += (sq.z * inv_nv - mz * mz) * wv.z;
    cost += (sq.w * inv_nv - mw * mw) * wv.w;
  }
  cost += breg[0];
  cost_out[idx] = cost;
}

// ---------------------------------------------------------------------------
// Fallback cost kernel (original layout) if ws is too small.
// ---------------------------------------------------------------------------
__global__ __launch_bounds__(256) void cost_kernel(
    const float* __restrict__ ref, const float* __restrict__ src,
    const float* __restrict__ dvals, const float* __restrict__ wreg,
    const float* __restrict__ breg, const float* __restrict__ pr,
    float* __restrict__ cost_out) {
  int idx = blockIdx.x * 256 + threadIdx.x;
  if (idx >= B * D * H * W) return;
  int w = idx % W;
  int h = (idx / W) % H;
  int d = (idx / (W * H)) % D;
  int b = idx / (W * H * D);
  float depth = dvals[b * D + d];
  float fx = (float)w, fy = (float)h;

  int   off[NSRC][4];
  float wgt[NSRC][4];
#pragma unroll
  for (int v = 0; v < NSRC; v++) {
    const float* p = pr + (v * B + b) * 12;
    float X = (p[0] * fx + p[1] * fy + p[2]) * depth + p[9];
    float Y = (p[3] * fx + p[4] * fy + p[5]) * depth + p[10];
    float Z = (p[6] * fx + p[7] * fy + p[8]) * depth + p[11];
    float px = X / Z, py = Y / Z;
    float x0f = floorf(px), y0f = floorf(py);
    float wx = px - x0f, wy = py - y0f;
    int x0 = (int)x0f, y0 = (int)y0f;
    int x1 = x0 + 1, y1 = y0 + 1;
    float vx0 = (x0 >= 0 && x0 < W) ? 1.f : 0.f;
    float vx1 = (x1 >= 0 && x1 < W) ? 1.f : 0.f;
    float vy0 = (y0 >= 0 && y0 < H) ? 1.f : 0.f;
    float vy1 = (y1 >= 0 && y1 < H) ? 1.f : 0.f;
    int cx0 = min(max(x0, 0), W - 1), cx1 = min(max(x1, 0), W - 1);
    int cy0 = min(max(y0, 0), H - 1), cy1 = min(max(y1, 0), H - 1);
    int base = (v * B + b) * C * HWsz;
    off[v][0] = base + cy0 * W + cx0;
    off[v][1] = base + cy0 * W + cx1;
    off[v][2] = base + cy1 * W + cx0;
    off[v][3] = base + cy1 * W + cx1;
    wgt[v][0] = (1.f - wx) * (1.f - wy) * vx0 * vy0;
    wgt[v][1] = wx * (1.f - wy) * vx1 * vy0;
    wgt[v][2] = (1.f - wx) * wy * vx0 * vy1;
    wgt[v][3] = wx * wy * vx1 * vy1;
  }

  int refoff = b * C * HWsz + h * W + w;
  const float inv_nv = 1.f / (float)NV;
  float cost = 0.f;
#pragma unroll 4
  for (int c = 0; c < C; c++) {
    float rv = ref[refoff + c * HWsz];
    float s = rv, sq = rv * rv;
#pragma unroll
    for (int v = 0; v < NSRC; v++) {
      int co = c * HWsz;
      float smp = wgt[v][0] * src[off[v][0] + co]
                + wgt[v][1] * src[off[v][1] + co]
                + wgt[v][2] * src[off[v][2] + co]
                + wgt[v][3] * src[off[v][3] + co];
      s += smp;
      sq += smp * smp;
    }
    float m = s * inv_nv;
    float var = sq * inv_nv - m * m;
    cost += var * wreg[c];
  }
  cost += breg[0];
  cost_out[idx] = cost;
}

// ---------------------------------------------------------------------------
// Softmax / depth / confidence per (b,h,w) column.
// ---------------------------------------------------------------------------
__global__ __launch_bounds__(256) void softmax_kernel(
    const float* __restrict__ dvals, float* __restrict__ out) {
  int idx = blockIdx.x * 256 + threadIdx.x;
  if (idx >= B * HWsz) return;
  int b = idx / HWsz;
  int hw = idx % HWsz;
  float* prob = out + 2 * B * HWsz;

  float p[D];
  float mx = -1e30f;
#pragma unroll
  for (int d = 0; d < D; d++) {
    p[d] = prob[(b * D + d) * HWsz + hw];
    mx = fmaxf(mx, p[d]);
  }
  float sum = 0.f;
#pragma unroll
  for (int d = 0; d < D; d++) {
    p[d] = expf(p[d] - mx);
    sum += p[d];
  }
  float inv = 1.f / sum;
  float depth = 0.f, didxf = 0.f;
#pragma unroll
  for (int d = 0; d < D; d++) {
    p[d] *= inv;
    depth += p[d] * dvals[b * D + d];
    didxf += p[d] * (float)d;
    prob[(b * D + d) * HWsz + hw] = p[d];
  }
  int di = (int)didxf;
  di = min(max(di, 0), D - 1);
  float conf = 0.f;
#pragma unroll
  for (int d = 0; d < D; d++) {
    conf += ((d == di) || (d == di + 1)) ? p[d] : 0.f;
  }
  out[idx] = depth;
  out[B * HWsz + idx] = conf;
}

extern "C" void kernel_launch(void* const* d_in, const int* in_sizes, int n_in,
                              void* d_out, int out_size, void* d_ws, size_t ws_size,
                              hipStream_t stream) {
  const float* ref_feature  = (const float*)d_in[0];
  const float* src_features = (const float*)d_in[1];
  const float* ref_proj     = (const float*)d_in[2];
  const float* src_projs    = (const float*)d_in[3];
  const float* depth_values = (const float*)d_in[4];
  const float* w_reg        = (const float*)d_in[5];
  const float* b_reg        = (const float*)d_in[6];

  float* out = (float*)d_out;
  float* ws  = (float*)d_ws;
  float* cost = out + 2 * B * HWsz;  // prob_volume region doubles as cost scratch

  setup_proj<<<1, 64, 0, stream>>>(ref_proj, src_projs, ws);

  int n1 = B * D * H * W;
  int nblk1 = (n1 + 255) / 256;

  if (ws_size >= (size_t)WS_FLOATS * sizeof(float)) {
    float* src_t = ws + SRC_T_OFF;
    float* ref_t = ws + REF_T_OFF;
    constexpr int BLKS_PER_PLANE = HWsz / 256;
    transpose_cl<<<NSRC * B * BLKS_PER_PLANE, 256, 0, stream>>>(src_features, src_t);
    transpose_cl<<<B * BLKS_PER_PLANE, 256, 0, stream>>>(ref_feature, ref_t);
    cost_cl_kernel<<<nblk1, 256, 0, stream>>>(
        ref_t, src_t, depth_values, w_reg, b_reg, ws + PROJ_OFF, cost);
  } else {
    cost_kernel<<<nblk1, 256, 0, stream>>>(
        ref_feature, src_features, depth_values, w_reg, b_reg, ws + PROJ_OFF, cost);
  }

  int n2 = B * HWsz;
  softmax_kernel<<<(n2 + 255) / 256, 256, 0, stream>>>(depth_values, out);
}

// Round 3
// 94.993 us; speedup vs baseline: 1.7140x; 1.7140x over previous
//
#include <hip/hip_runtime.h>

constexpr int B = 2, C = 32, H = 96, W = 128, D = 48, NSRC = 2;
constexpr int NV = NSRC + 1;
constexpr int HWsz = H * W;

// ---------------------------------------------------------------------------
// Setup: per (view, b) compute rot(3x3) + trans(3) of  src_p @ inv(ref_p)
// ---------------------------------------------------------------------------
__global__ void setup_proj(const float* __restrict__ ref_proj,
                           const float* __restrict__ src_projs,
                           float* __restrict__ ws) {
  int t = threadIdx.x;
  if (t >= NSRC * B) return;
  int v = t / B, b = t % B;
  const float* rp = ref_proj + b * 32;
  const float* sp = src_projs + (v * B + b) * 32;

  double Kr[3][3], Er[3][4], Ks[3][3], Es[3][4];
  for (int r = 0; r < 3; r++)
    for (int c = 0; c < 3; c++) { Kr[r][c] = rp[16 + r * 4 + c]; Ks[r][c] = sp[16 + r * 4 + c]; }
  for (int r = 0; r < 3; r++)
    for (int c = 0; c < 4; c++) { Er[r][c] = rp[r * 4 + c]; Es[r][c] = sp[r * 4 + c]; }

  double Ar[3][3], tr[3], As[3][3], ts[3];
  for (int r = 0; r < 3; r++) {
    for (int c = 0; c < 3; c++) {
      double a = 0, s = 0;
      for (int k = 0; k < 3; k++) { a += Kr[r][k] * Er[k][c]; s += Ks[r][k] * Es[k][c]; }
      Ar[r][c] = a; As[r][c] = s;
    }
    double a = 0, s = 0;
    for (int k = 0; k < 3; k++) { a += Kr[r][k] * Er[k][3]; s += Ks[r][k] * Es[k][3]; }
    tr[r] = a; ts[r] = s;
  }

  double det = Ar[0][0] * (Ar[1][1] * Ar[2][2] - Ar[1][2] * Ar[2][1])
             - Ar[0][1] * (Ar[1][0] * Ar[2][2] - Ar[1][2] * Ar[2][0])
             + Ar[0][2] * (Ar[1][0] * Ar[2][1] - Ar[1][1] * Ar[2][0]);
  double inv[3][3];
  inv[0][0] =  (Ar[1][1] * Ar[2][2] - Ar[1][2] * Ar[2][1]) / det;
  inv[0][1] = -(Ar[0][1] * Ar[2][2] - Ar[0][2] * Ar[2][1]) / det;
  inv[0][2] =  (Ar[0][1] * Ar[1][2] - Ar[0][2] * Ar[1][1]) / det;
  inv[1][0] = -(Ar[1][0] * Ar[2][2] - Ar[1][2] * Ar[2][0]) / det;
  inv[1][1] =  (Ar[0][0] * Ar[2][2] - Ar[0][2] * Ar[2][0]) / det;
  inv[1][2] = -(Ar[0][0] * Ar[1][2] - Ar[0][2] * Ar[1][0]) / det;
  inv[2][0] =  (Ar[1][0] * Ar[2][1] - Ar[1][1] * Ar[2][0]) / det;
  inv[2][1] = -(Ar[0][0] * Ar[2][1] - Ar[0][1] * Ar[2][0]) / det;
  inv[2][2] =  (Ar[0][0] * Ar[1][1] - Ar[0][1] * Ar[1][0]) / det;

  double rot[3][3], trans[3];
  for (int r = 0; r < 3; r++)
    for (int c = 0; c < 3; c++) {
      double a = 0;
      for (int k = 0; k < 3; k++) a += As[r][k] * inv[k][c];
      rot[r][c] = a;
    }
  for (int r = 0; r < 3; r++) {
    double a = 0;
    for (int k = 0; k < 3; k++) a += rot[r][k] * tr[k];
    trans[r] = ts[r] - a;
  }

  float* o = ws + t * 12;
  for (int r = 0; r < 3; r++)
    for (int c = 0; c < 3; c++) o[r * 3 + c] = (float)rot[r][c];
  for (int r = 0; r < 3; r++) o[9 + r] = (float)trans[r];
}

// ---------------------------------------------------------------------------
// Cost kernel: one thread per (b, depth-pair, h, w). Original [c][hw] layout
// (lane-coalesced gathers). Corners loaded as float2 rows; clip validity
// folded into precomputed .x/.y weights. Ref load shared across the 2 depths.
// ---------------------------------------------------------------------------
__global__ __launch_bounds__(256) void cost2_kernel(
    const float* __restrict__ ref, const float* __restrict__ src,
    const float* __restrict__ dvals, const float* __restrict__ wreg,
    const float* __restrict__ breg, const float* __restrict__ pr,
    float* __restrict__ cost_out) {
  constexpr int DH = D / 2;
  int idx = blockIdx.x * 256 + threadIdx.x;
  if (idx >= B * DH * H * W) return;
  int w = idx % W;
  int h = (idx / W) % H;
  int dp = (idx / (W * H)) % DH;
  int b = idx / (W * H * DH);
  float fx = (float)w, fy = (float)h;

  int   off0[2][NSRC], off1[2][NSRC];
  float wA0[2][NSRC], wB0[2][NSRC], wA1[2][NSRC], wB1[2][NSRC];
#pragma unroll
  for (int dd = 0; dd < 2; dd++) {
    int d = dp * 2 + dd;
    float depth = dvals[b * D + d];
#pragma unroll
    for (int v = 0; v < NSRC; v++) {
      const float* p = pr + (v * B + b) * 12;
      float X = (p[0] * fx + p[1] * fy + p[2]) * depth + p[9];
      float Y = (p[3] * fx + p[4] * fy + p[5]) * depth + p[10];
      float Z = (p[6] * fx + p[7] * fy + p[8]) * depth + p[11];
      float px = X / Z, py = Y / Z;
      float x0f = floorf(px), y0f = floorf(py);
      float wx = px - x0f, wy = py - y0f;
      int x0 = (int)x0f, y0 = (int)y0f;
      int lx = min(max(x0, 0), W - 2);
      int cy0 = min(max(y0, 0), H - 1);
      int cy1 = min(max(y0 + 1, 0), H - 1);
      float vx0 = (x0 >= 0 && x0 < W) ? 1.f : 0.f;
      float vx1 = (x0 + 1 >= 0 && x0 + 1 < W) ? 1.f : 0.f;
      float vy0 = (y0 >= 0 && y0 < H) ? 1.f : 0.f;
      float vy1 = (y0 + 1 >= 0 && y0 + 1 < H) ? 1.f : 0.f;
      // ax: weight of F[lx], bx: weight of F[lx+1] (x-direction, validity folded)
      float ax = (x0 == lx) ? (1.f - wx) * vx0 : ((x0 == lx - 1) ? wx * vx1 : 0.f);
      float bx = (x0 == lx) ? wx * vx1 : ((x0 == lx + 1) ? (1.f - wx) * vx0 : 0.f);
      float wy0v = (1.f - wy) * vy0;
      float wy1v = wy * vy1;
      int base = (v * B + b) * C * HWsz;
      off0[dd][v] = base + cy0 * W + lx;
      off1[dd][v] = base + cy1 * W + lx;
      wA0[dd][v] = ax * wy0v; wB0[dd][v] = bx * wy0v;
      wA1[dd][v] = ax * wy1v; wB1[dd][v] = bx * wy1v;
    }
  }

  int refoff = b * C * HWsz + h * W + w;
  const float inv_nv = 1.f / (float)NV;
  float cost0 = 0.f, cost1 = 0.f;
#pragma unroll 4
  for (int c = 0; c < C; c++) {
    float rv = ref[refoff + c * HWsz];
    float wc = wreg[c];
    float s0 = rv, sq0 = rv * rv;
    float s1 = rv, sq1 = rv * rv;
#pragma unroll
    for (int v = 0; v < NSRC; v++) {
      {
        float2 t0 = ((const float2*)(src + off0[0][v]))[c * (HWsz / 2)];
        float2 t1 = ((const float2*)(src + off1[0][v]))[c * (HWsz / 2)];
        float smp = wA0[0][v] * t0.x + wB0[0][v] * t0.y
                  + wA1[0][v] * t1.x + wB1[0][v] * t1.y;
        s0 += smp;
        sq0 = fmaf(smp, smp, sq0);
      }
      {
        float2 t0 = ((const float2*)(src + off0[1][v]))[c * (HWsz / 2)];
        float2 t1 = ((const float2*)(src + off1[1][v]))[c * (HWsz / 2)];
        float smp = wA0[1][v] * t0.x + wB0[1][v] * t0.y
                  + wA1[1][v] * t1.x + wB1[1][v] * t1.y;
        s1 += smp;
        sq1 = fmaf(smp, smp, sq1);
      }
    }
    float m0 = s0 * inv_nv;
    float m1 = s1 * inv_nv;
    cost0 += (sq0 * inv_nv - m0 * m0) * wc;
    cost1 += (sq1 * inv_nv - m1 * m1) * wc;
  }
  float bb = breg[0];
  int o = ((b * D + dp * 2) * H + h) * W + w;
  cost_out[o] = cost0 + bb;
  cost_out[o + HWsz] = cost1 + bb;
}

// ---------------------------------------------------------------------------
// Softmax / depth / confidence per (b,h,w) column.
// ---------------------------------------------------------------------------
__global__ __launch_bounds__(256) void softmax_kernel(
    const float* __restrict__ dvals, float* __restrict__ out) {
  int idx = blockIdx.x * 256 + threadIdx.x;
  if (idx >= B * HWsz) return;
  int b = idx / HWsz;
  int hw = idx % HWsz;
  float* prob = out + 2 * B * HWsz;

  float p[D];
  float mx = -1e30f;
#pragma unroll
  for (int d = 0; d < D; d++) {
    p[d] = prob[(b * D + d) * HWsz + hw];
    mx = fmaxf(mx, p[d]);
  }
  float sum = 0.f;
#pragma unroll
  for (int d = 0; d < D; d++) {
    p[d] = expf(p[d] - mx);
    sum += p[d];
  }
  float inv = 1.f / sum;
  float depth = 0.f, didxf = 0.f;
#pragma unroll
  for (int d = 0; d < D; d++) {
    p[d] *= inv;
    depth += p[d] * dvals[b * D + d];
    didxf += p[d] * (float)d;
    prob[(b * D + d) * HWsz + hw] = p[d];
  }
  int di = (int)didxf;
  di = min(max(di, 0), D - 1);
  float conf = 0.f;
#pragma unroll
  for (int d = 0; d < D; d++) {
    conf += ((d == di) || (d == di + 1)) ? p[d] : 0.f;
  }
  out[idx] = depth;
  out[B * HWsz + idx] = conf;
}

extern "C" void kernel_launch(void* const* d_in, const int* in_sizes, int n_in,
                              void* d_out, int out_size, void* d_ws, size_t ws_size,
                              hipStream_t stream) {
  const float* ref_feature  = (const float*)d_in[0];
  const float* src_features = (const float*)d_in[1];
  const float* ref_proj     = (const float*)d_in[2];
  const float* src_projs    = (const float*)d_in[3];
  const float* depth_values = (const float*)d_in[4];
  const float* w_reg        = (const float*)d_in[5];
  const float* b_reg        = (const float*)d_in[6];

  float* out = (float*)d_out;
  float* ws  = (float*)d_ws;
  float* cost = out + 2 * B * HWsz;  // prob_volume region doubles as cost scratch

  setup_proj<<<1, 64, 0, stream>>>(ref_proj, src_projs, ws);

  int n1 = B * (D / 2) * H * W;
  cost2_kernel<<<(n1 + 255) / 256, 256, 0, stream>>>(
      ref_feature, src_features, depth_values, w_reg, b_reg, ws, cost);

  int n2 = B * HWsz;
  softmax_kernel<<<(n2 + 255) / 256, 256, 0, stream>>>(depth_values, out);
}